// Round 1
// baseline (150.439 us; speedup 1.0000x reference)
//
#include <hip/hip_runtime.h>
#include <hip/hip_cooperative_groups.h>
#include <math.h>

namespace cg = cooperative_groups;

#define NB 4096
#define NN 10000
#define ND 256
#define ALPHA 0.2f
#define CS 16                 // rows per chunk
#define NG (NN / CS)          // 625 chunks (exact)
#define SCHUNK 25             // chunks per superchunk
#define NSUPER (NG / SCHUNK)  // 25 superchunks (exact)
#define MSEGS 25
#define SEGLEN (NN / MSEGS)   // 400 (exact, divisible by 4)
#define ZELEMS (NN + 2 * NSUPER * ND + 2 * NSUPER)  // rank + SSA + SSC + ssa0 + ssc0
#define GRID 1024             // 4 blocks/CU x 256 CUs co-resident

typedef unsigned long long u64;

struct Args {
  const float *P, *V, *K;
  float *out;
  u64 *tk;
  int *zreg, *rank;
  float *SSA, *SSC, *ssa0, *ssc0;
  float *t, *s, *tsort, *eA, *eC;
  int *idxs, *kk;
  float *SA, *SC, *sa0, *sc0;
};

// ---- Phase A: zero accumulators; t_n = V[n].Wn, s_b = P[b].Wp (one wave/row);
//      sortable u64 keys (float-monotone uint32 << 14 | index).
__device__ __forceinline__ void phaseA(const Args& a, int bid, int tid, int nblk) {
  int gtid = bid * 256 + tid;
  int nth = nblk * 256;
  for (int i = gtid; i < ZELEMS; i += nth) a.zreg[i] = 0;
  int lane = tid & 63;
  int wv = bid * 4 + (tid >> 6);
  for (int j = wv; j < NN + NB; j += nblk * 4) {
    bool isn = (j < NN);
    const float* row = isn ? a.V + (size_t)j * ND : a.P + (size_t)(j - NN) * ND;
    const float* wgt = isn ? a.K + ND : a.K;
    float4 r  = ((const float4*)row)[lane];
    float4 kx = ((const float4*)wgt)[lane];
    float acc = r.x * kx.x + r.y * kx.y + r.z * kx.z + r.w * kx.w;
    #pragma unroll
    for (int off = 32; off; off >>= 1) acc += __shfl_down(acc, off, 64);
    if (lane == 0) {
      if (isn) {
        a.t[j] = acc;
        unsigned bits = __float_as_uint(acc);
        unsigned key = bits ^ (((int)bits >> 31) | 0x80000000u);  // monotone map
        a.tk[j] = ((u64)key << 14) | (unsigned)j;
      } else {
        a.s[j - NN] = acc;
      }
    }
  }
}

// ---- Phase B: rank[n] = #{m : tk[m] < tk[n]}, wave-uniform key loads.
__device__ __forceinline__ void phaseB(const Args& a, int bid, int tid, int nblk) {
  for (int tb = bid; tb < MSEGS * 40; tb += nblk) {
    int seg = tb / 40;
    int n = (tb % 40) * 256 + tid;
    u64 kn = (n < NN) ? a.tk[n] : ~0ull;
    int m0 = seg * SEGLEN;
    int m1 = m0 + SEGLEN;  // SEGLEN*MSEGS == NN exactly
    int r = 0;
    #pragma unroll 1
    for (int m = m0; m < m1; m += 4) {
      u64 x0 = a.tk[m], x1 = a.tk[m + 1], x2 = a.tk[m + 2], x3 = a.tk[m + 3];
      r += (x0 < kn) + (x1 < kn) + (x2 < kn) + (x3 < kn);
    }
    if (n < NN && r) atomicAdd(&a.rank[n], r);
  }
}

// ---- Phase C: scatter into sorted order + exp factors.
__device__ __forceinline__ void phaseC(const Args& a, int bid, int tid, int nblk) {
  int nth = nblk * 256;
  for (int n = bid * 256 + tid; n < NN; n += nth) {
    int r = a.rank[n];
    float tn = a.t[n];
    a.tsort[r] = tn;
    a.eA[r] = __expf(tn);
    a.eC[r] = __expf(ALPHA * tn);
    a.idxs[r] = n;
  }
}

// ---- Phase D: per-chunk sums + atomic superchunk sums; binary searches -> kk[b].
__device__ __forceinline__ void phaseD(const Args& a, int bid, int tid, int nblk) {
  for (int g = bid; g < NG + NB / 256; g += nblk) {
    if (g < NG) {
      int base = g * CS, d = tid;
      float accA = 0.f, accC = 0.f, sa = 0.f, sc = 0.f;
      #pragma unroll
      for (int jj = 0; jj < CS; ++jj) {
        int i = base + jj;
        float ea = a.eA[i], ec = a.eC[i];
        float v = a.V[(size_t)a.idxs[i] * ND + d];
        accA += ea * v; accC += ec * v;
        sa += ea; sc += ec;
      }
      a.SA[(size_t)g * ND + d] = accA;
      a.SC[(size_t)g * ND + d] = accC;
      int gs = g / SCHUNK;
      atomicAdd(&a.SSA[(size_t)gs * ND + d], accA);
      atomicAdd(&a.SSC[(size_t)gs * ND + d], accC);
      if (d == 0) {
        a.sa0[g] = sa; a.sc0[g] = sc;
        atomicAdd(&a.ssa0[gs], sa);
        atomicAdd(&a.ssc0[gs], sc);
      }
    } else {
      int b = (g - NG) * 256 + tid;  // 16 blocks x 256 = 4096 = NB
      float key = -a.s[b];
      int lo = 0, hi = NN;  // lower_bound: first idx with tsort[idx] >= key
      while (lo < hi) {
        int mid = (lo + hi) >> 1;
        if (a.tsort[mid] < key) lo = mid + 1; else hi = mid;
      }
      a.kk[b] = lo;
    }
  }
}

// ---- Phase E: A-side suffix sums + C-side prefix sums, fused epilogue.
__device__ __forceinline__ void phaseE(const Args& a, int bid, int tid, int nblk) {
  for (int b = bid; b < NB; b += nblk) {
    int d = tid;
    int k = a.kk[b];
    int g = k >> 4;          // chunk idx; k==NN -> g==NG
    int gs = g / SCHUNK;     // superchunk idx; g==NG -> gs==NSUPER
    float suffA = 0.f, prefC = 0.f, suffa = 0.f, prefc = 0.f;
    for (int q = gs; q < NSUPER; ++q) {
      suffA += a.SSA[(size_t)q * ND + d];
      suffa += a.ssa0[q];
    }
    for (int q = 0; q < gs; ++q) {
      prefC += a.SSC[(size_t)q * ND + d];
      prefc += a.ssc0[q];
    }
    for (int j = gs * SCHUNK; j < g; ++j) {
      suffA -= a.SA[(size_t)j * ND + d];
      prefC += a.SC[(size_t)j * ND + d];
      suffa -= a.sa0[j];
      prefc += a.sc0[j];
    }
    for (int i = g << 4; i < k; ++i) {
      float ea = a.eA[i], ec = a.eC[i];
      float v = a.V[(size_t)a.idxs[i] * ND + d];
      suffA -= ea * v; prefC += ec * v;
      suffa -= ea;     prefc += ec;
    }
    float sb = a.s[b];
    float ea = __expf(sb), ec = __expf(ALPHA * sb);
    float l = ea * suffa + ec * prefc;
    float agg = (ea * suffA + ec * prefC) / l;
    a.out[(size_t)b * ND + d] = a.P[(size_t)b * ND + d] + agg;
  }
}

// Single cooperative kernel: phases separated by grid-wide barriers.
__global__ __launch_bounds__(256, 4) void fused_all(Args a) {
  cg::grid_group gg = cg::this_grid();
  int tid = threadIdx.x, bid = blockIdx.x, nblk = gridDim.x;
  phaseA(a, bid, tid, nblk);
  gg.sync();
  phaseB(a, bid, tid, nblk);
  gg.sync();
  phaseC(a, bid, tid, nblk);
  gg.sync();
  phaseD(a, bid, tid, nblk);
  gg.sync();
  phaseE(a, bid, tid, nblk);
}

// Fallback: same device code, one launch per phase (kernel boundary = sync).
__global__ __launch_bounds__(256, 4) void fused_one(Args a, int ph) {
  int tid = threadIdx.x, bid = blockIdx.x, nblk = gridDim.x;
  switch (ph) {
    case 0: phaseA(a, bid, tid, nblk); break;
    case 1: phaseB(a, bid, tid, nblk); break;
    case 2: phaseC(a, bid, tid, nblk); break;
    case 3: phaseD(a, bid, tid, nblk); break;
    case 4: phaseE(a, bid, tid, nblk); break;
  }
}

extern "C" void kernel_launch(void* const* d_in, const int* in_sizes, int n_in,
                              void* d_out, int out_size, void* d_ws, size_t ws_size,
                              hipStream_t stream) {
  Args a;
  a.P = (const float*)d_in[0];   // (B, D)
  a.V = (const float*)d_in[1];   // (N, D)
  a.K = (const float*)d_in[2];   // (2D, 1)
  a.out = (float*)d_out;

  char* w = (char*)d_ws;
  a.tk = (u64*)w;    w += sizeof(u64) * NN;          // 8B-aligned first
  // --- zeroed-by-phaseA region (contiguous): rank, SSA, SSC, ssa0, ssc0 ---
  a.zreg = (int*)w;
  a.rank = (int*)w;  w += sizeof(int) * NN;
  a.SSA = (float*)w; w += sizeof(float) * NSUPER * ND;
  a.SSC = (float*)w; w += sizeof(float) * NSUPER * ND;
  a.ssa0 = (float*)w; w += sizeof(float) * NSUPER;
  a.ssc0 = (float*)w; w += sizeof(float) * NSUPER;
  // --- rest ---
  a.t = (float*)w;     w += sizeof(float) * NN;
  a.s = (float*)w;     w += sizeof(float) * NB;
  a.tsort = (float*)w; w += sizeof(float) * NN;
  a.eA = (float*)w;    w += sizeof(float) * NN;
  a.eC = (float*)w;    w += sizeof(float) * NN;
  a.idxs = (int*)w;    w += sizeof(int) * NN;
  a.kk = (int*)w;      w += sizeof(int) * NB;
  a.SA = (float*)w;    w += sizeof(float) * (size_t)NG * ND;
  a.SC = (float*)w;    w += sizeof(float) * (size_t)NG * ND;
  a.sa0 = (float*)w;   w += sizeof(float) * NG;
  a.sc0 = (float*)w;   w += sizeof(float) * NG;

  // One-time host-side occupancy check (no device ops; graph-capture safe).
  static int coop_ok = -1;
  if (coop_ok < 0) {
    int nb = 0;
    if (hipOccupancyMaxActiveBlocksPerMultiprocessor(
            &nb, (const void*)fused_all, 256, 0) != hipSuccess) nb = 0;
    coop_ok = (nb >= GRID / 256) ? 1 : 0;   // need 4 blocks/CU on 256 CUs
  }

  if (coop_ok) {
    void* kargs[] = {(void*)&a};
    hipLaunchCooperativeKernel((const void*)fused_all, dim3(GRID), dim3(256),
                               kargs, 0, stream);
  } else {
    for (int ph = 0; ph < 5; ++ph)
      fused_one<<<dim3(GRID), dim3(256), 0, stream>>>(a, ph);
  }
}

// Round 3
// 145.373 us; speedup vs baseline: 1.0348x; 1.0348x over previous
//
#include <hip/hip_runtime.h>
#include <math.h>

#define NB 4096
#define NN 10000
#define ND 256
#define ALPHA 0.2f
#define CS 16                 // rows per chunk
#define NG (NN / CS)          // 625 chunks (exact)
#define SCHUNK 25             // chunks per superchunk
#define NSUPER (NG / SCHUNK)  // 25 superchunks (exact)
#define RSEGS 16              // rank segments per block
#define RSEGLEN (NN / RSEGS)  // 625 keys per segment (exact)
#define ZELEMS (2 * NSUPER * ND + 2 * NSUPER)  // SSA + SSC + ssa0 + ssc0

typedef unsigned long long u64;

// --- 1) dot scores t_n=V[n]·Wn, s_b=P[b]·Wp (one wave per row); sortable
// u64 keys tk[n] (strict total order: float-monotone uint32 <<14 | index);
// zero the atomic accumulator region (SSA/SSC/ssa0/ssc0).
__global__ __launch_bounds__(256) void k_dot(
    const float* __restrict__ P, const float* __restrict__ V,
    const float* __restrict__ K,
    float* __restrict__ t, float* __restrict__ s, u64* __restrict__ tk,
    int* __restrict__ zero_region) {
  int gt = blockIdx.x * 256 + threadIdx.x;
  if (gt < ZELEMS) zero_region[gt] = 0;
  int j = blockIdx.x * 4 + (threadIdx.x >> 6);
  int lane = threadIdx.x & 63;
  if (j >= NN + NB) return;
  const float* row; const float* wv; int oi; bool isn;
  if (j < NN) { row = V + (size_t)j * ND; wv = K + ND; oi = j; isn = true; }
  else        { row = P + (size_t)(j - NN) * ND; wv = K; oi = j - NN; isn = false; }
  float4 r  = ((const float4*)row)[lane];
  float4 kx = ((const float4*)wv)[lane];
  float acc = r.x * kx.x + r.y * kx.y + r.z * kx.z + r.w * kx.w;
  #pragma unroll
  for (int off = 32; off; off >>= 1) acc += __shfl_down(acc, off, 64);
  if (lane == 0) {
    if (isn) {
      t[oi] = acc;
      unsigned bits = __float_as_uint(acc);
      unsigned key = bits ^ (((int)bits >> 31) | 0x80000000u);  // monotone map
      tk[oi] = ((u64)key << 14) | (unsigned)oi;
    } else {
      s[oi] = acc;
    }
  }
}

// --- 2) fused rank + scatter: block g owns n in [16g, 16g+16).
// 256 threads = 16 n-slots x 16 key-segments; each thread counts
// #{m in its segment : tk[m] < tk[n]}; LDS-reduce over segments gives the
// FULL rank inside the block -> scatter immediately (no atomics, no 2nd pass).
__global__ __launch_bounds__(256) void k_ranksc(
    const u64* __restrict__ tk, const float* __restrict__ t,
    float* __restrict__ tsort, float* __restrict__ eA, float* __restrict__ eC,
    int* __restrict__ idxs) {
  __shared__ int lr[CS][RSEGS + 1];
  int g = blockIdx.x;                 // 0..624
  int nl = threadIdx.x & 15;          // n slot
  int seg = threadIdx.x >> 4;         // key segment
  int n = g * CS + nl;
  u64 kn = tk[n];
  int m0 = seg * RSEGLEN;
  int m1 = m0 + RSEGLEN;              // RSEGS*RSEGLEN == NN exactly
  int r = 0;
  int m = m0;
  #pragma unroll 1
  for (; m + 4 <= m1; m += 4) {
    u64 a = tk[m], b = tk[m + 1], c = tk[m + 2], d = tk[m + 3];
    r += (a < kn) + (b < kn) + (c < kn) + (d < kn);
  }
  for (; m < m1; ++m) r += (tk[m] < kn);
  lr[nl][seg] = r;
  __syncthreads();
  if (threadIdx.x < CS) {
    int rr = 0;
    #pragma unroll
    for (int q = 0; q < RSEGS; ++q) rr += lr[threadIdx.x][q];
    int n2 = g * CS + threadIdx.x;
    float tn = t[n2];
    tsort[rr] = tn;
    eA[rr] = __expf(tn);
    eC[rr] = __expf(ALPHA * tn);
    idxs[rr] = n2;
  }
}

// --- 3) blocks <NG: per-chunk sums + atomic superchunk sums.
//        blocks >=NG (16 of them): per-patient binary searches -> kk[b].
__global__ __launch_bounds__(256) void k_chunk(
    const float* __restrict__ eA, const float* __restrict__ eC,
    const int* __restrict__ idxs, const float* __restrict__ V,
    const float* __restrict__ s, const float* __restrict__ tsort,
    float* __restrict__ SA, float* __restrict__ SC,
    float* __restrict__ sa0, float* __restrict__ sc0,
    float* __restrict__ SSA, float* __restrict__ SSC,
    float* __restrict__ ssa0, float* __restrict__ ssc0,
    int* __restrict__ kk) {
  int g = blockIdx.x, d = threadIdx.x;
  if (g < NG) {
    int base = g * CS;
    float accA = 0.f, accC = 0.f, sa = 0.f, sc = 0.f;
    #pragma unroll
    for (int j = 0; j < CS; ++j) {
      int i = base + j;
      float ea = eA[i], ec = eC[i];
      float v = V[(size_t)idxs[i] * ND + d];
      accA += ea * v; accC += ec * v;
      sa += ea; sc += ec;
    }
    SA[(size_t)g * ND + d] = accA;
    SC[(size_t)g * ND + d] = accC;
    int gs = g / SCHUNK;
    atomicAdd(&SSA[(size_t)gs * ND + d], accA);
    atomicAdd(&SSC[(size_t)gs * ND + d], accC);
    if (d == 0) {
      sa0[g] = sa; sc0[g] = sc;
      atomicAdd(&ssa0[gs], sa);
      atomicAdd(&ssc0[gs], sc);
    }
  } else {
    int b = (g - NG) * 256 + d;           // 16 blocks x 256 = 4096 = NB
    float key = -s[b];
    int lo = 0, hi = NN;  // lower_bound: first idx with tsort[idx] >= key
    while (lo < hi) {
      int mid = (lo + hi) >> 1;
      if (tsort[mid] < key) lo = mid + 1; else hi = mid;
    }
    kk[b] = lo;
  }
}

// --- 4) finalize: A-side as suffix sums, C-side as prefix sums (25 SS rows
// + <=24 chunk rows + <=15 V rows per block), fused epilogue.
__global__ __launch_bounds__(256) void k_finalize(
    const float* __restrict__ P, const float* __restrict__ V,
    const float* __restrict__ s, const int* __restrict__ kk,
    const float* __restrict__ eA, const float* __restrict__ eC,
    const int* __restrict__ idxs,
    const float* __restrict__ SA, const float* __restrict__ SC,
    const float* __restrict__ sa0, const float* __restrict__ sc0,
    const float* __restrict__ SSA, const float* __restrict__ SSC,
    const float* __restrict__ ssa0, const float* __restrict__ ssc0,
    float* __restrict__ out) {
  int b = blockIdx.x, d = threadIdx.x;
  int k = kk[b];
  int g = k >> 4;          // chunk idx; k==NN -> g==NG
  int gs = g / SCHUNK;     // superchunk idx; g==NG -> gs==NSUPER
  float suffA = 0.f, prefC = 0.f, suffa = 0.f, prefc = 0.f;
  for (int q = gs; q < NSUPER; ++q) {
    suffA += SSA[(size_t)q * ND + d];
    suffa += ssa0[q];
  }
  for (int q = 0; q < gs; ++q) {
    prefC += SSC[(size_t)q * ND + d];
    prefc += ssc0[q];
  }
  for (int j = gs * SCHUNK; j < g; ++j) {
    suffA -= SA[(size_t)j * ND + d];
    prefC += SC[(size_t)j * ND + d];
    suffa -= sa0[j];
    prefc += sc0[j];
  }
  for (int i = g << 4; i < k; ++i) {
    float ea = eA[i], ec = eC[i];
    float v = V[(size_t)idxs[i] * ND + d];
    suffA -= ea * v; prefC += ec * v;
    suffa -= ea;     prefc += ec;
  }
  float sb = s[b];
  float ea = __expf(sb), ec = __expf(ALPHA * sb);
  float l = ea * suffa + ec * prefc;
  float agg = (ea * suffA + ec * prefC) / l;
  out[(size_t)b * ND + d] = P[(size_t)b * ND + d] + agg;
}

extern "C" void kernel_launch(void* const* d_in, const int* in_sizes, int n_in,
                              void* d_out, int out_size, void* d_ws, size_t ws_size,
                              hipStream_t stream) {
  const float* P = (const float*)d_in[0];   // (B, D)
  const float* V = (const float*)d_in[1];   // (N, D)
  const float* K = (const float*)d_in[2];   // (2D, 1)
  float* out = (float*)d_out;

  char* w = (char*)d_ws;
  u64*   tk    = (u64*)w;   w += sizeof(u64) * NN;        // 8B-aligned first
  // --- zeroed-by-k_dot region (contiguous): SSA, SSC, ssa0, ssc0 ---
  int*   zreg  = (int*)w;
  float* SSA   = (float*)w; w += sizeof(float) * NSUPER * ND;
  float* SSC   = (float*)w; w += sizeof(float) * NSUPER * ND;
  float* ssa0  = (float*)w; w += sizeof(float) * NSUPER;
  float* ssc0  = (float*)w; w += sizeof(float) * NSUPER;
  // --- rest ---
  float* t     = (float*)w; w += sizeof(float) * NN;
  float* s     = (float*)w; w += sizeof(float) * NB;
  float* tsort = (float*)w; w += sizeof(float) * NN;
  float* eA    = (float*)w; w += sizeof(float) * NN;
  float* eC    = (float*)w; w += sizeof(float) * NN;
  int*   idxs  = (int*)w;   w += sizeof(int) * NN;
  int*   kk    = (int*)w;   w += sizeof(int) * NB;
  float* SA    = (float*)w; w += sizeof(float) * (size_t)NG * ND;
  float* SC    = (float*)w; w += sizeof(float) * (size_t)NG * ND;
  float* sa0   = (float*)w; w += sizeof(float) * NG;
  float* sc0   = (float*)w; w += sizeof(float) * NG;

  k_dot<<<(NN + NB + 3) / 4, 256, 0, stream>>>(P, V, K, t, s, tk, zreg);
  k_ranksc<<<NG, 256, 0, stream>>>(tk, t, tsort, eA, eC, idxs);
  k_chunk<<<NG + NB / 256, 256, 0, stream>>>(eA, eC, idxs, V, s, tsort,
                                             SA, SC, sa0, sc0,
                                             SSA, SSC, ssa0, ssc0, kk);
  k_finalize<<<NB, 256, 0, stream>>>(P, V, s, kk, eA, eC, idxs,
                                     SA, SC, sa0, sc0, SSA, SSC, ssa0, ssc0, out);
}

// Round 4
// 126.244 us; speedup vs baseline: 1.1916x; 1.1515x over previous
//
#include <hip/hip_runtime.h>
#include <math.h>

#define NB 4096
#define NN 10000
#define ND 256
#define ALPHA 0.2f
#define CS 16                 // rows per chunk
#define NG (NN / CS)          // 625 chunks (exact)
#define SCHUNK 25             // chunks per superchunk
#define NSUPER (NG / SCHUNK)  // 25 superchunks (exact)
#define RSEGS 16              // rank segments per block (16 n-slots x 16 segs)
#define TILE 2000             // keys staged in LDS per pass
#define NTILES (NN / TILE)    // 5 (exact)
#define TSEG (TILE / RSEGS)   // 125 keys per thread per tile (exact)
#define ZELEMS (2 * NSUPER * ND + 2 * NSUPER)  // SSA + SSC + ssa0 + ssc0

typedef unsigned long long u64;

// --- 1) dot scores t_n=V[n]·Wn, s_b=P[b]·Wp (one wave per row); sortable
// u64 keys tk[n] (strict total order: float-monotone uint32 <<14 | index);
// zero the atomic accumulator region (SSA/SSC/ssa0/ssc0).
__global__ __launch_bounds__(256) void k_dot(
    const float* __restrict__ P, const float* __restrict__ V,
    const float* __restrict__ K,
    float* __restrict__ t, float* __restrict__ s, u64* __restrict__ tk,
    int* __restrict__ zero_region) {
  int gt = blockIdx.x * 256 + threadIdx.x;
  if (gt < ZELEMS) zero_region[gt] = 0;
  int j = blockIdx.x * 4 + (threadIdx.x >> 6);
  int lane = threadIdx.x & 63;
  if (j >= NN + NB) return;
  const float* row; const float* wv; int oi; bool isn;
  if (j < NN) { row = V + (size_t)j * ND; wv = K + ND; oi = j; isn = true; }
  else        { row = P + (size_t)(j - NN) * ND; wv = K; oi = j - NN; isn = false; }
  float4 r  = ((const float4*)row)[lane];
  float4 kx = ((const float4*)wv)[lane];
  float acc = r.x * kx.x + r.y * kx.y + r.z * kx.z + r.w * kx.w;
  #pragma unroll
  for (int off = 32; off; off >>= 1) acc += __shfl_down(acc, off, 64);
  if (lane == 0) {
    if (isn) {
      t[oi] = acc;
      unsigned bits = __float_as_uint(acc);
      unsigned key = bits ^ (((int)bits >> 31) | 0x80000000u);  // monotone map
      tk[oi] = ((u64)key << 14) | (unsigned)oi;
    } else {
      s[oi] = acc;
    }
  }
}

// --- 2) fused rank + scatter, LDS-tiled: block g owns n in [16g, 16g+16).
// Loop 5 tiles of 2000 keys: cooperative coalesced load into LDS, then
// 256 threads = 16 n-slots x 16 segments scan 125 LDS keys each
// (same-address broadcast within an n-group is conflict-free).
// LDS-reduce over segments gives the FULL rank in-block -> scatter.
__global__ __launch_bounds__(256) void k_ranksc(
    const u64* __restrict__ tk, const float* __restrict__ t,
    float* __restrict__ tsort, float* __restrict__ eA, float* __restrict__ eC,
    int* __restrict__ idxs) {
  __shared__ u64 kt[TILE];
  __shared__ int lr[CS][RSEGS + 1];
  int g = blockIdx.x;                 // 0..624
  int nl = threadIdx.x & 15;          // n slot
  int seg = threadIdx.x >> 4;         // key segment within tile
  u64 kn = tk[g * CS + nl];
  int r = 0;
  for (int tile = 0; tile < NTILES; ++tile) {
    for (int m = threadIdx.x; m < TILE; m += 256)
      kt[m] = tk[tile * TILE + m];
    __syncthreads();
    int m0 = seg * TSEG;
    #pragma unroll 5
    for (int m = m0; m < m0 + TSEG; ++m) r += (kt[m] < kn);
    __syncthreads();
  }
  lr[nl][seg] = r;
  __syncthreads();
  if (threadIdx.x < CS) {
    int rr = 0;
    #pragma unroll
    for (int q = 0; q < RSEGS; ++q) rr += lr[threadIdx.x][q];
    int n2 = g * CS + threadIdx.x;
    float tn = t[n2];
    tsort[rr] = tn;
    eA[rr] = __expf(tn);
    eC[rr] = __expf(ALPHA * tn);
    idxs[rr] = n2;
  }
}

// --- 3) blocks <NG: per-chunk sums + atomic superchunk sums.
//        blocks >=NG (16 of them): per-patient binary searches -> kk[b].
__global__ __launch_bounds__(256) void k_chunk(
    const float* __restrict__ eA, const float* __restrict__ eC,
    const int* __restrict__ idxs, const float* __restrict__ V,
    const float* __restrict__ s, const float* __restrict__ tsort,
    float* __restrict__ SA, float* __restrict__ SC,
    float* __restrict__ sa0, float* __restrict__ sc0,
    float* __restrict__ SSA, float* __restrict__ SSC,
    float* __restrict__ ssa0, float* __restrict__ ssc0,
    int* __restrict__ kk) {
  int g = blockIdx.x, d = threadIdx.x;
  if (g < NG) {
    int base = g * CS;
    float accA = 0.f, accC = 0.f, sa = 0.f, sc = 0.f;
    #pragma unroll
    for (int j = 0; j < CS; ++j) {
      int i = base + j;
      float ea = eA[i], ec = eC[i];
      float v = V[(size_t)idxs[i] * ND + d];
      accA += ea * v; accC += ec * v;
      sa += ea; sc += ec;
    }
    SA[(size_t)g * ND + d] = accA;
    SC[(size_t)g * ND + d] = accC;
    int gs = g / SCHUNK;
    atomicAdd(&SSA[(size_t)gs * ND + d], accA);
    atomicAdd(&SSC[(size_t)gs * ND + d], accC);
    if (d == 0) {
      sa0[g] = sa; sc0[g] = sc;
      atomicAdd(&ssa0[gs], sa);
      atomicAdd(&ssc0[gs], sc);
    }
  } else {
    int b = (g - NG) * 256 + d;           // 16 blocks x 256 = 4096 = NB
    float key = -s[b];
    int lo = 0, hi = NN;  // lower_bound: first idx with tsort[idx] >= key
    while (lo < hi) {
      int mid = (lo + hi) >> 1;
      if (tsort[mid] < key) lo = mid + 1; else hi = mid;
    }
    kk[b] = lo;
  }
}

// --- 4) finalize: A-side as suffix sums, C-side as prefix sums (25 SS rows
// + <=24 chunk rows + <=15 V rows per block), fused epilogue.
__global__ __launch_bounds__(256) void k_finalize(
    const float* __restrict__ P, const float* __restrict__ V,
    const float* __restrict__ s, const int* __restrict__ kk,
    const float* __restrict__ eA, const float* __restrict__ eC,
    const int* __restrict__ idxs,
    const float* __restrict__ SA, const float* __restrict__ SC,
    const float* __restrict__ sa0, const float* __restrict__ sc0,
    const float* __restrict__ SSA, const float* __restrict__ SSC,
    const float* __restrict__ ssa0, const float* __restrict__ ssc0,
    float* __restrict__ out) {
  int b = blockIdx.x, d = threadIdx.x;
  int k = kk[b];
  int g = k >> 4;          // chunk idx; k==NN -> g==NG
  int gs = g / SCHUNK;     // superchunk idx; g==NG -> gs==NSUPER
  float suffA = 0.f, prefC = 0.f, suffa = 0.f, prefc = 0.f;
  for (int q = gs; q < NSUPER; ++q) {
    suffA += SSA[(size_t)q * ND + d];
    suffa += ssa0[q];
  }
  for (int q = 0; q < gs; ++q) {
    prefC += SSC[(size_t)q * ND + d];
    prefc += ssc0[q];
  }
  for (int j = gs * SCHUNK; j < g; ++j) {
    suffA -= SA[(size_t)j * ND + d];
    prefC += SC[(size_t)j * ND + d];
    suffa -= sa0[j];
    prefc += sc0[j];
  }
  for (int i = g << 4; i < k; ++i) {
    float ea = eA[i], ec = eC[i];
    float v = V[(size_t)idxs[i] * ND + d];
    suffA -= ea * v; prefC += ec * v;
    suffa -= ea;     prefc += ec;
  }
  float sb = s[b];
  float ea = __expf(sb), ec = __expf(ALPHA * sb);
  float l = ea * suffa + ec * prefc;
  float agg = (ea * suffA + ec * prefC) / l;
  out[(size_t)b * ND + d] = P[(size_t)b * ND + d] + agg;
}

extern "C" void kernel_launch(void* const* d_in, const int* in_sizes, int n_in,
                              void* d_out, int out_size, void* d_ws, size_t ws_size,
                              hipStream_t stream) {
  const float* P = (const float*)d_in[0];   // (B, D)
  const float* V = (const float*)d_in[1];   // (N, D)
  const float* K = (const float*)d_in[2];   // (2D, 1)
  float* out = (float*)d_out;

  char* w = (char*)d_ws;
  u64*   tk    = (u64*)w;   w += sizeof(u64) * NN;        // 8B-aligned first
  // --- zeroed-by-k_dot region (contiguous): SSA, SSC, ssa0, ssc0 ---
  int*   zreg  = (int*)w;
  float* SSA   = (float*)w; w += sizeof(float) * NSUPER * ND;
  float* SSC   = (float*)w; w += sizeof(float) * NSUPER * ND;
  float* ssa0  = (float*)w; w += sizeof(float) * NSUPER;
  float* ssc0  = (float*)w; w += sizeof(float) * NSUPER;
  // --- rest ---
  float* t     = (float*)w; w += sizeof(float) * NN;
  float* s     = (float*)w; w += sizeof(float) * NB;
  float* tsort = (float*)w; w += sizeof(float) * NN;
  float* eA    = (float*)w; w += sizeof(float) * NN;
  float* eC    = (float*)w; w += sizeof(float) * NN;
  int*   idxs  = (int*)w;   w += sizeof(int) * NN;
  int*   kk    = (int*)w;   w += sizeof(int) * NB;
  float* SA    = (float*)w; w += sizeof(float) * (size_t)NG * ND;
  float* SC    = (float*)w; w += sizeof(float) * (size_t)NG * ND;
  float* sa0   = (float*)w; w += sizeof(float) * NG;
  float* sc0   = (float*)w; w += sizeof(float) * NG;

  k_dot<<<(NN + NB + 3) / 4, 256, 0, stream>>>(P, V, K, t, s, tk, zreg);
  k_ranksc<<<NG, 256, 0, stream>>>(tk, t, tsort, eA, eC, idxs);
  k_chunk<<<NG + NB / 256, 256, 0, stream>>>(eA, eC, idxs, V, s, tsort,
                                             SA, SC, sa0, sc0,
                                             SSA, SSC, ssa0, ssc0, kk);
  k_finalize<<<NB, 256, 0, stream>>>(P, V, s, kk, eA, eC, idxs,
                                     SA, SC, sa0, sc0, SSA, SSC, ssa0, ssc0, out);
}